// Round 10
// baseline (133.354 us; speedup 1.0000x reference)
//
#include <hip/hip_runtime.h>

#define RES 128
#define NCELLS (RES * RES * RES)        // 2097152
#define CASC 4
#define GRID_TOTAL (CASC * NCELLS)      // 8388608
#define NBYTES (GRID_TOTAL / 8)         // 1048576

typedef float f32x2 __attribute__((ext_vector_type(2)));

// inverse of instant-ngp expand_bits: gather every 3rd bit
__device__ __forceinline__ unsigned compact3(unsigned v) {
    v &= 0x49249249u;
    v = (v | (v >> 2))  & 0xC30C30C3u;
    v = (v | (v >> 4))  & 0x0F00F00Fu;
    v = (v | (v >> 8))  & 0xFF0000FFu;
    v = (v | (v >> 16)) & 0x3FFu;
    return v;
}

__device__ __forceinline__ f32x2 pk_fma(f32x2 a, f32x2 b, f32x2 c) {
    return __builtin_elementwise_fma(a, b, c);   // v_pk_fma_f32, IEEE fma per lane
}

// One thread per morton index m; 4 cascades as two f32x2 lanes-pairs.
// j-outer: one ds_read_b128 + one ds_read_b32 per j feeds all 4 cascades.
__global__ __launch_bounds__(256) void dg_main(
    const float* __restrict__ dgrid,   // [CASC, NCELLS]
    const float* __restrict__ jit,     // [CASC, NCELLS, 3]
    const float* __restrict__ W1,      // [3,32]
    const float* __restrict__ b1,      // [32]
    const float* __restrict__ W2,      // [32]
    const float* __restrict__ b2,      // [1]
    float* __restrict__ out,           // [CASC, NCELLS]
    double* __restrict__ sum_ws)
{
    // wq[j] = {W1[j], W1[32+j], W1[64+j], b1[j]};  w2s[j] = W2[j]
    __shared__ float4 wq[32];
    __shared__ float w2s[32];
    if (threadIdx.x < 32) {
        const int j = threadIdx.x;
        wq[j] = make_float4(W1[j], W1[32 + j], W1[64 + j], b1[j]);
        w2s[j] = W2[j];
    }
    __syncthreads();

    const int m = blockIdx.x * 256 + threadIdx.x;
    const unsigned x = compact3((unsigned)m);
    const unsigned y = compact3((unsigned)m >> 1);
    const unsigned z = compact3((unsigned)m >> 2);
    const int c = (int)((x << 14) | (y << 7) | z);   // linear cell index

    const float cx = (float)x, cy = (float)y, cz = (float)z;
    const float bb2 = b2[0];

    // ---- hoisted global loads (latency exposed once) ----
    const float* jp0 = jit + ((size_t)0 * NCELLS + (size_t)c) * 3;
    const float* jp1 = jit + ((size_t)1 * NCELLS + (size_t)c) * 3;
    const float* jp2 = jit + ((size_t)2 * NCELLS + (size_t)c) * 3;
    const float* jp3 = jit + ((size_t)3 * NCELLS + (size_t)c) * 3;
    const float jx0 = jp0[0], jy0 = jp0[1], jz0 = jp0[2];
    const float jx1 = jp1[0], jy1 = jp1[1], jz1 = jp1[2];
    const float jx2 = jp2[0], jy2 = jp2[1], jz2 = jp2[2];
    const float jx3 = jp3[0], jy3 = jp3[1], jz3 = jp3[2];
    const float g0 = dgrid[(size_t)0 * NCELLS + m];
    const float g1 = dgrid[(size_t)1 * NCELLS + m];
    const float g2 = dgrid[(size_t)2 * NCELLS + m];
    const float g3 = dgrid[(size_t)3 * NCELLS + m];

    // world positions (identical op order to reference), packed {casc0,casc1},{casc2,casc3}
    const float px0 = ((cx + jx0) * (1.0f / 128.0f) - 0.5f) * 1.0f;
    const float py0 = ((cy + jy0) * (1.0f / 128.0f) - 0.5f) * 1.0f;
    const float pz0 = ((cz + jz0) * (1.0f / 128.0f) - 0.5f) * 1.0f;
    const float px1 = ((cx + jx1) * (1.0f / 128.0f) - 0.5f) * 2.0f;
    const float py1 = ((cy + jy1) * (1.0f / 128.0f) - 0.5f) * 2.0f;
    const float pz1 = ((cz + jz1) * (1.0f / 128.0f) - 0.5f) * 2.0f;
    const float px2 = ((cx + jx2) * (1.0f / 128.0f) - 0.5f) * 4.0f;
    const float py2 = ((cy + jy2) * (1.0f / 128.0f) - 0.5f) * 4.0f;
    const float pz2 = ((cz + jz2) * (1.0f / 128.0f) - 0.5f) * 4.0f;
    const float px3 = ((cx + jx3) * (1.0f / 128.0f) - 0.5f) * 8.0f;
    const float py3 = ((cy + jy3) * (1.0f / 128.0f) - 0.5f) * 8.0f;
    const float pz3 = ((cz + jz3) * (1.0f / 128.0f) - 0.5f) * 8.0f;

    const f32x2 pxA = {px0, px1}, pxB = {px2, px3};
    const f32x2 pyA = {py0, py1}, pyB = {py2, py3};
    const f32x2 pzA = {pz0, pz1}, pzB = {pz2, pz3};
    const f32x2 zer = {0.0f, 0.0f};
    f32x2 accA = {bb2, bb2}, accB = {bb2, bb2};

    #pragma unroll
    for (int j = 0; j < 32; ++j) {
        const float4 w = wq[j];
        const float u = w2s[j];
        const f32x2 wx = {w.x, w.x}, wy = {w.y, w.y}, wz = {w.z, w.z};
        const f32x2 wb = {w.w, w.w}, uu = {u, u};
        f32x2 hA = pk_fma(pxA, wx, wb);          // a = fma(px, W1r0, b1)
        f32x2 hB = pk_fma(pxB, wx, wb);
        hA = pk_fma(pyA, wy, hA);
        hB = pk_fma(pyB, wy, hB);
        hA = pk_fma(pzA, wz, hA);
        hB = pk_fma(pzB, wz, hB);
        hA = __builtin_elementwise_max(hA, zer); // relu
        hB = __builtin_elementwise_max(hB, zer);
        accA = pk_fma(hA, uu, accA);             // acc = fma(h, W2, acc)
        accB = pk_fma(hB, uu, accB);
    }

    double lsum = 0.0;

#define LEVEL(L, ACC, G) { \
        const float a = ACC; \
        const float d = fmaxf(a, 0.0f) + log1pf(expf(-fabsf(a))); \
        const float nv = (G >= 0.0f && d >= 0.0f) ? fmaxf(G * 0.95f, d) : G; \
        out[(size_t)L * NCELLS + m] = nv; \
        lsum += (double)nv; }

    LEVEL(0, accA.x, g0)
    LEVEL(1, accA.y, g1)
    LEVEL(2, accB.x, g2)
    LEVEL(3, accB.y, g3)
#undef LEVEL

    // block reduction (f64) then one atomicAdd per block
    __shared__ double sdata[256];
    sdata[threadIdx.x] = lsum;
    __syncthreads();
    #pragma unroll
    for (int s = 128; s > 0; s >>= 1) {
        if (threadIdx.x < s) sdata[threadIdx.x] += sdata[threadIdx.x + s];
        __syncthreads();
    }
    if (threadIdx.x == 0) atomicAdd(sum_ws, sdata[0]);
}

__global__ void dg_finalize(const double* __restrict__ sum_ws,
                            float* __restrict__ out,
                            float* __restrict__ thr_ws)
{
    const double mean = *sum_ws / (double)GRID_TOTAL;
    const float mf = (float)mean;
    out[GRID_TOTAL] = mf;                 // mean_density output
    *thr_ws = fminf(mf, 2.0f);            // thresh for bitfield pass
}

// One thread per output byte: read 8 consecutive grid floats, pack bits, emit as float.
__global__ __launch_bounds__(256) void dg_bitfield(
    const float* __restrict__ grid,
    const float* __restrict__ thr_ws,
    float* __restrict__ outb)
{
    const int i = blockIdx.x * 256 + threadIdx.x;
    const float t = *thr_ws;
    const float4* p = (const float4*)(grid + (size_t)i * 8);
    const float4 a = p[0];
    const float4 b = p[1];
    int v = 0;
    v |= (a.x > t) ? 1   : 0;
    v |= (a.y > t) ? 2   : 0;
    v |= (a.z > t) ? 4   : 0;
    v |= (a.w > t) ? 8   : 0;
    v |= (b.x > t) ? 16  : 0;
    v |= (b.y > t) ? 32  : 0;
    v |= (b.z > t) ? 64  : 0;
    v |= (b.w > t) ? 128 : 0;
    outb[i] = (float)v;
}

extern "C" void kernel_launch(void* const* d_in, const int* in_sizes, int n_in,
                              void* d_out, int out_size, void* d_ws, size_t ws_size,
                              hipStream_t stream) {
    const float* dgrid = (const float*)d_in[0];
    const float* jit   = (const float*)d_in[1];
    const float* W1    = (const float*)d_in[2];
    const float* b1    = (const float*)d_in[3];
    const float* W2    = (const float*)d_in[4];
    const float* b2    = (const float*)d_in[5];

    float* out = (float*)d_out;
    double* sum_ws = (double*)d_ws;
    float* thr_ws = (float*)((char*)d_ws + 8);

    hipMemsetAsync(d_ws, 0, 8, stream);   // zero the f64 accumulator (capture-safe)

    dg_main<<<NCELLS / 256, 256, 0, stream>>>(dgrid, jit, W1, b1, W2, b2, out, sum_ws);
    dg_finalize<<<1, 1, 0, stream>>>(sum_ws, out, thr_ws);
    dg_bitfield<<<NBYTES / 256, 256, 0, stream>>>(out, thr_ws, out + GRID_TOTAL + 1);
}

// Round 11
// 123.663 us; speedup vs baseline: 1.0784x; 1.0784x over previous
//
#include <hip/hip_runtime.h>

#define RES 128
#define NCELLS (RES * RES * RES)        // 2097152
#define CASC 4
#define GRID_TOTAL (CASC * NCELLS)      // 8388608
#define NBYTES (GRID_TOTAL / 8)         // 1048576
#define PTS 4
#define MAIN_BLOCKS (NCELLS / (256 * PTS))   // 2048

typedef float f32x2 __attribute__((ext_vector_type(2)));

// inverse of instant-ngp expand_bits: gather every 3rd bit
__device__ __forceinline__ unsigned compact3(unsigned v) {
    v &= 0x49249249u;
    v = (v | (v >> 2))  & 0xC30C30C3u;
    v = (v | (v >> 4))  & 0x0F00F00Fu;
    v = (v | (v >> 8))  & 0xFF0000FFu;
    v = (v | (v >> 16)) & 0x3FFu;
    return v;
}

__device__ __forceinline__ f32x2 pk_fma(f32x2 a, f32x2 b, f32x2 c) {
    return __builtin_elementwise_fma(a, b, c);   // v_pk_fma_f32, IEEE fma per lane
}

// 2048 blocks x 256 threads x 4 sequential morton points (full one-shot residency:
// 8 blocks/CU). Per point: R10's packed 4-cascade MLP body unchanged.
__global__ __launch_bounds__(256) void dg_main(
    const float* __restrict__ dgrid,   // [CASC, NCELLS]
    const float* __restrict__ jit,     // [CASC, NCELLS, 3]
    const float* __restrict__ W1,      // [3,32]
    const float* __restrict__ b1,      // [32]
    const float* __restrict__ W2,      // [32]
    const float* __restrict__ b2,      // [1]
    float* __restrict__ out,           // [CASC, NCELLS]
    double* __restrict__ sum_ws)
{
    // wq[j] = {W1[j], W1[32+j], W1[64+j], b1[j]};  w2s[j] = W2[j]
    __shared__ float4 wq[32];
    __shared__ float w2s[32];
    __shared__ double sdata[4];
    if (threadIdx.x < 32) {
        const int j = threadIdx.x;
        wq[j] = make_float4(W1[j], W1[32 + j], W1[64 + j], b1[j]);
        w2s[j] = W2[j];
    }
    __syncthreads();

    const float bb2 = b2[0];
    double lsum = 0.0;

    #pragma unroll 1                       // sequential points: keeps VGPR ~R10 level
    for (int k = 0; k < PTS; ++k) {
        const int m = blockIdx.x * (256 * PTS) + k * 256 + (int)threadIdx.x;
        const unsigned x = compact3((unsigned)m);
        const unsigned y = compact3((unsigned)m >> 1);
        const unsigned z = compact3((unsigned)m >> 2);
        const int c = (int)((x << 14) | (y << 7) | z);   // linear cell index

        const float cx = (float)x, cy = (float)y, cz = (float)z;

        // hoisted global loads for this point (latency exposed once per point)
        const float* jp0 = jit + ((size_t)0 * NCELLS + (size_t)c) * 3;
        const float* jp1 = jit + ((size_t)1 * NCELLS + (size_t)c) * 3;
        const float* jp2 = jit + ((size_t)2 * NCELLS + (size_t)c) * 3;
        const float* jp3 = jit + ((size_t)3 * NCELLS + (size_t)c) * 3;
        const float jx0 = jp0[0], jy0 = jp0[1], jz0 = jp0[2];
        const float jx1 = jp1[0], jy1 = jp1[1], jz1 = jp1[2];
        const float jx2 = jp2[0], jy2 = jp2[1], jz2 = jp2[2];
        const float jx3 = jp3[0], jy3 = jp3[1], jz3 = jp3[2];
        const float g0 = dgrid[(size_t)0 * NCELLS + m];
        const float g1 = dgrid[(size_t)1 * NCELLS + m];
        const float g2 = dgrid[(size_t)2 * NCELLS + m];
        const float g3 = dgrid[(size_t)3 * NCELLS + m];

        // world positions (identical op order to reference)
        const float px0 = ((cx + jx0) * (1.0f / 128.0f) - 0.5f) * 1.0f;
        const float py0 = ((cy + jy0) * (1.0f / 128.0f) - 0.5f) * 1.0f;
        const float pz0 = ((cz + jz0) * (1.0f / 128.0f) - 0.5f) * 1.0f;
        const float px1 = ((cx + jx1) * (1.0f / 128.0f) - 0.5f) * 2.0f;
        const float py1 = ((cy + jy1) * (1.0f / 128.0f) - 0.5f) * 2.0f;
        const float pz1 = ((cz + jz1) * (1.0f / 128.0f) - 0.5f) * 2.0f;
        const float px2 = ((cx + jx2) * (1.0f / 128.0f) - 0.5f) * 4.0f;
        const float py2 = ((cy + jy2) * (1.0f / 128.0f) - 0.5f) * 4.0f;
        const float pz2 = ((cz + jz2) * (1.0f / 128.0f) - 0.5f) * 4.0f;
        const float px3 = ((cx + jx3) * (1.0f / 128.0f) - 0.5f) * 8.0f;
        const float py3 = ((cy + jy3) * (1.0f / 128.0f) - 0.5f) * 8.0f;
        const float pz3 = ((cz + jz3) * (1.0f / 128.0f) - 0.5f) * 8.0f;

        const f32x2 pxA = {px0, px1}, pxB = {px2, px3};
        const f32x2 pyA = {py0, py1}, pyB = {py2, py3};
        const f32x2 pzA = {pz0, pz1}, pzB = {pz2, pz3};
        const f32x2 zer = {0.0f, 0.0f};
        f32x2 accA = {bb2, bb2}, accB = {bb2, bb2};

        #pragma unroll
        for (int j = 0; j < 32; ++j) {
            const float4 w = wq[j];
            const float u = w2s[j];
            const f32x2 wx = {w.x, w.x}, wy = {w.y, w.y}, wz = {w.z, w.z};
            const f32x2 wb = {w.w, w.w}, uu = {u, u};
            f32x2 hA = pk_fma(pxA, wx, wb);
            f32x2 hB = pk_fma(pxB, wx, wb);
            hA = pk_fma(pyA, wy, hA);
            hB = pk_fma(pyB, wy, hB);
            hA = pk_fma(pzA, wz, hA);
            hB = pk_fma(pzB, wz, hB);
            hA = __builtin_elementwise_max(hA, zer);
            hB = __builtin_elementwise_max(hB, zer);
            accA = pk_fma(hA, uu, accA);
            accB = pk_fma(hB, uu, accB);
        }

#define LEVEL(L, ACC, G) { \
        const float a = ACC; \
        const float d = fmaxf(a, 0.0f) + log1pf(expf(-fabsf(a))); \
        const float nv = (G >= 0.0f && d >= 0.0f) ? fmaxf(G * 0.95f, d) : G; \
        out[(size_t)L * NCELLS + m] = nv; \
        lsum += (double)nv; }

        LEVEL(0, accA.x, g0)
        LEVEL(1, accA.y, g1)
        LEVEL(2, accB.x, g2)
        LEVEL(3, accB.y, g3)
#undef LEVEL
    }

    // wave-level f64 reduction -> 4 LDS partials -> one atomic per block
    #pragma unroll
    for (int s = 32; s > 0; s >>= 1) lsum += __shfl_down(lsum, s);
    const int wid = threadIdx.x >> 6;
    const int lane = threadIdx.x & 63;
    if (lane == 0) sdata[wid] = lsum;
    __syncthreads();
    if (threadIdx.x == 0)
        atomicAdd(sum_ws, (sdata[0] + sdata[1]) + (sdata[2] + sdata[3]));
}

__global__ void dg_finalize(const double* __restrict__ sum_ws,
                            float* __restrict__ out,
                            float* __restrict__ thr_ws)
{
    const double mean = *sum_ws / (double)GRID_TOTAL;
    const float mf = (float)mean;
    out[GRID_TOTAL] = mf;                 // mean_density output
    *thr_ws = fminf(mf, 2.0f);            // thresh for bitfield pass
}

// One thread per output byte: read 8 consecutive grid floats, pack bits, emit as float.
__global__ __launch_bounds__(256) void dg_bitfield(
    const float* __restrict__ grid,
    const float* __restrict__ thr_ws,
    float* __restrict__ outb)
{
    const int i = blockIdx.x * 256 + threadIdx.x;
    const float t = *thr_ws;
    const float4* p = (const float4*)(grid + (size_t)i * 8);
    const float4 a = p[0];
    const float4 b = p[1];
    int v = 0;
    v |= (a.x > t) ? 1   : 0;
    v |= (a.y > t) ? 2   : 0;
    v |= (a.z > t) ? 4   : 0;
    v |= (a.w > t) ? 8   : 0;
    v |= (b.x > t) ? 16  : 0;
    v |= (b.y > t) ? 32  : 0;
    v |= (b.z > t) ? 64  : 0;
    v |= (b.w > t) ? 128 : 0;
    outb[i] = (float)v;
}

extern "C" void kernel_launch(void* const* d_in, const int* in_sizes, int n_in,
                              void* d_out, int out_size, void* d_ws, size_t ws_size,
                              hipStream_t stream) {
    const float* dgrid = (const float*)d_in[0];
    const float* jit   = (const float*)d_in[1];
    const float* W1    = (const float*)d_in[2];
    const float* b1    = (const float*)d_in[3];
    const float* W2    = (const float*)d_in[4];
    const float* b2    = (const float*)d_in[5];

    float* out = (float*)d_out;
    double* sum_ws = (double*)d_ws;
    float* thr_ws = (float*)((char*)d_ws + 8);

    hipMemsetAsync(d_ws, 0, 8, stream);   // zero the f64 accumulator (capture-safe)

    dg_main<<<MAIN_BLOCKS, 256, 0, stream>>>(dgrid, jit, W1, b1, W2, b2, out, sum_ws);
    dg_finalize<<<1, 1, 0, stream>>>(sum_ws, out, thr_ws);
    dg_bitfield<<<NBYTES / 256, 256, 0, stream>>>(out, thr_ws, out + GRID_TOTAL + 1);
}